// Round 4
// baseline (401.818 us; speedup 1.0000x reference)
//
#include <hip/hip_runtime.h>

#define DM   1024
#define DI   2048
#define DSZ  16
#define DTR  64
#define BB   2
#define LL   2048
#define MM   (BB*LL)   // 4096

using bfrag8 = __attribute__((ext_vector_type(8))) short;
using facc4  = __attribute__((ext_vector_type(4))) float;

__device__ __forceinline__ unsigned short f2bf(float f) {
  unsigned int u = __float_as_uint(f);
  u += 0x7fffu + ((u >> 16) & 1u);
  return (unsigned short)(u >> 16);
}

__device__ __forceinline__ float sigmoidf_(float x) { return 1.f / (1.f + __expf(-x)); }
__device__ __forceinline__ float softplusf_(float x) { return (x > 20.f) ? x : log1pf(__expf(x)); }

__device__ __forceinline__ void gload16(const void* g, void* l) {
  __builtin_amdgcn_global_load_lds(
      (__attribute__((address_space(1))) void*)(g),
      (__attribute__((address_space(3))) void*)(l), 16, 0, 0);
}

// ---------------- elementwise converts ----------------

__global__ __launch_bounds__(256) void cvt_bf16(const float* __restrict__ s,
                                                unsigned short* __restrict__ d, int n) {
  int i = (blockIdx.x * 256 + threadIdx.x) * 4;
  if (i + 3 < n) {
    float4 v = *(const float4*)(s + i);
    ushort4 o;
    o.x = f2bf(v.x); o.y = f2bf(v.y); o.z = f2bf(v.z); o.w = f2bf(v.w);
    *(ushort4*)(d + i) = o;
  }
}

// src f32 [R][C] -> dst bf16 [C][R]; R,C multiples of 32
__global__ __launch_bounds__(256) void transpose_cvt(const float* __restrict__ src,
                                                     unsigned short* __restrict__ dst,
                                                     int R, int C) {
  __shared__ float tile[32][33];
  int c0 = blockIdx.x * 32, r0 = blockIdx.y * 32;
  for (int i = threadIdx.y; i < 32; i += 8)
    tile[i][threadIdx.x] = src[(size_t)(r0 + i) * C + c0 + threadIdx.x];
  __syncthreads();
  for (int i = threadIdx.y; i < 32; i += 8)
    dst[(size_t)(c0 + i) * R + r0 + threadIdx.x] = f2bf(tile[threadIdx.x][i]);
}

__global__ __launch_bounds__(256) void extract_dr(const float* __restrict__ dbc,
                                                  unsigned short* __restrict__ dr) {
  int i = blockIdx.x * 256 + threadIdx.x;
  if (i < MM * DTR) {
    int row = i >> 6, c = i & 63;
    dr[i] = f2bf(dbc[(size_t)row * 96 + c]);
  }
}

// ---------------- depthwise causal conv + silu ----------------
// xi = xr[:, 0:DI]; u = silu(conv(xi)); writes f32 and bf16
__global__ __launch_bounds__(256) void conv_silu(const float* __restrict__ xr,
                                                 const float* __restrict__ cw,
                                                 const float* __restrict__ cb,
                                                 float* __restrict__ uf,
                                                 unsigned short* __restrict__ ubf) {
  const int d = blockIdx.x * 256 + threadIdx.x;
  const int b = blockIdx.z;
  const int t0 = blockIdx.y * 64;
  const float w0 = cw[d * 4 + 0], w1 = cw[d * 4 + 1], w2 = cw[d * 4 + 2], w3 = cw[d * 4 + 3];
  const float bias = cb[d];
  const size_t base = ((size_t)b * LL) * (2 * DI) + d;
  float xm3 = (t0 >= 3) ? xr[base + (size_t)(t0 - 3) * (2 * DI)] : 0.f;
  float xm2 = (t0 >= 2) ? xr[base + (size_t)(t0 - 2) * (2 * DI)] : 0.f;
  float xm1 = (t0 >= 1) ? xr[base + (size_t)(t0 - 1) * (2 * DI)] : 0.f;
  for (int t = t0; t < t0 + 64; ++t) {
    float x0 = xr[base + (size_t)t * (2 * DI)];
    float a = bias + w0 * xm3 + w1 * xm2 + w2 * xm1 + w3 * x0;
    float uu = a * sigmoidf_(a);
    size_t oi = ((size_t)b * LL + t) * DI + d;
    uf[oi] = uu;
    ubf[oi] = f2bf(uu);
    xm3 = xm2; xm2 = xm1; xm1 = x0;
  }
}

// ---------------- bf16 MFMA GEMM:  C[M][N] = A[M][K] * Bt[N][K]^T ----------------
// EPI: 0 = store f32; 1 = softplus(v + bias[col]); 2 = atomicAdd (split-K)
template<int BM, int BN, int WMN, int WNN, int MF, int NF, int EPI>
__global__ __launch_bounds__(256, 2) void gemm_bf16(const unsigned short* __restrict__ A,
                                                    const unsigned short* __restrict__ Bt,
                                                    float* __restrict__ C,
                                                    const float* __restrict__ bias,
                                                    int M, int N, int K, int kLen) {
  static_assert(WMN * WNN == 4 && WMN * MF * 16 == BM && WNN * NF * 16 == BN, "geom");
  __shared__ unsigned short smem[(BM + BN) * 32];
  unsigned short* As = smem;
  unsigned short* Bs = smem + BM * 32;
  const int tid = threadIdx.x;
  const int wave = tid >> 6, lane = tid & 63;
  const int tM = blockIdx.y * BM, tN = blockIdx.x * BN;
  const int k0 = blockIdx.z * kLen;
  const int lrow = lane >> 2, lq = lane & 3;
  const int wm = wave / WNN, wn = wave % WNN;
  const int fr = lane & 15, kg = lane >> 4;

  facc4 acc[MF][NF];
#pragma unroll
  for (int mi = 0; mi < MF; ++mi)
#pragma unroll
    for (int ni = 0; ni < NF; ++ni)
#pragma unroll
      for (int r = 0; r < 4; ++r) acc[mi][ni][r] = 0.f;

  for (int kk = k0; kk < k0 + kLen; kk += 32) {
    __syncthreads();
    // stage A tile: rows of 64B, swizzled source so swizzled reads see logical data
    for (int r = wave; r < BM / 16; r += 4) {
      int row = r * 16 + lrow;
      int lcb = (lq ^ ((row >> 1) & 3)) << 4;
      const char* src = (const char*)(A + (size_t)(tM + row) * K + kk) + lcb;
      gload16(src, (char*)As + r * 1024);
    }
    for (int r = wave; r < BN / 16; r += 4) {
      int row = r * 16 + lrow;
      int lcb = (lq ^ ((row >> 1) & 3)) << 4;
      const char* src = (const char*)(Bt + (size_t)(tN + row) * K + kk) + lcb;
      gload16(src, (char*)Bs + r * 1024);
    }
    __syncthreads();  // drains vmcnt before ds_read

    bfrag8 af[MF], bfr[NF];
#pragma unroll
    for (int mi = 0; mi < MF; ++mi) {
      int row = wm * (MF * 16) + mi * 16 + fr;
      af[mi] = *(const bfrag8*)((const char*)As + row * 64 + ((kg ^ ((row >> 1) & 3)) << 4));
    }
#pragma unroll
    for (int ni = 0; ni < NF; ++ni) {
      int row = wn * (NF * 16) + ni * 16 + fr;
      bfr[ni] = *(const bfrag8*)((const char*)Bs + row * 64 + ((kg ^ ((row >> 1) & 3)) << 4));
    }
#pragma unroll
    for (int mi = 0; mi < MF; ++mi)
#pragma unroll
      for (int ni = 0; ni < NF; ++ni)
        acc[mi][ni] = __builtin_amdgcn_mfma_f32_16x16x32_bf16(af[mi], bfr[ni], acc[mi][ni], 0, 0, 0);
  }

  const int orow = tM + wm * (MF * 16), ocol = tN + wn * (NF * 16);
#pragma unroll
  for (int mi = 0; mi < MF; ++mi)
#pragma unroll
    for (int ni = 0; ni < NF; ++ni)
#pragma unroll
      for (int r = 0; r < 4; ++r) {
        int row = orow + mi * 16 + kg * 4 + r;
        int col = ocol + ni * 16 + fr;
        float v = acc[mi][ni][r];
        size_t idx = (size_t)row * N + col;
        if (EPI == 0)      C[idx] = v;
        else if (EPI == 1) C[idx] = softplusf_(v + bias[col]);
        else               atomicAdd(&C[idx], v);
      }
}

// ---------------- fused selective scan ----------------
// block = 16 channels x 16 states; 16-step LDS chunks, double-buffered
__global__ __launch_bounds__(256) void scan_kernel(const float* __restrict__ delta,
                                                   const float* __restrict__ dbc,
                                                   const float* __restrict__ u,
                                                   const float* __restrict__ xr,
                                                   const float* __restrict__ A_log,
                                                   const float* __restrict__ Dv,
                                                   unsigned short* __restrict__ ybf) {
  const int tid = threadIdx.x;
  const int ci = tid >> 4, n = tid & 15;     // compute role: channel, state
  const int lt = tid >> 4, lc = tid & 15;    // load/epilogue role: t, channel
  const int ch0 = blockIdx.x * 16;
  const int b = ch0 / DI;
  const int d0 = ch0 % DI;
  const float Adn = -__expf(A_log[(d0 + ci) * DSZ + n]);
  const float Dd = Dv[d0 + lc];              // used in epilogue (channel = lc)
  __shared__ float sdel[2][16][16], su[2][16][16], sres[2][16][16], sB[2][16][16], sC[2][16][16];
  __shared__ float sp[16][16][20];           // +4 pad: conflict-free transpose reduce
  const size_t rb = (size_t)b * LL;

  { // prefetch chunk 0
    const size_t row = rb + lt;
    sdel[0][lt][lc] = delta[row * DI + d0 + lc];
    su[0][lt][lc]   = u[row * DI + d0 + lc];
    sres[0][lt][lc] = xr[row * (2 * DI) + DI + d0 + lc];
    sB[0][lt][lc]   = dbc[row * 96 + DTR + lc];
    sC[0][lt][lc]   = dbc[row * 96 + DTR + DSZ + lc];
  }
  __syncthreads();

  float h = 0.f;
  const int nch = LL / 16;
  for (int c = 0; c < nch; ++c) {
    const int cur = c & 1;
    float r0 = 0, r1 = 0, r2 = 0, r3 = 0, r4 = 0;
    const bool nxt = (c + 1) < nch;
    if (nxt) {  // issue next-chunk loads early (hide under compute)
      const size_t row = rb + (size_t)(c + 1) * 16 + lt;
      r0 = delta[row * DI + d0 + lc];
      r1 = u[row * DI + d0 + lc];
      r2 = xr[row * (2 * DI) + DI + d0 + lc];
      r3 = dbc[row * 96 + DTR + lc];
      r4 = dbc[row * 96 + DTR + DSZ + lc];
    }
    // phase A: 16 sequential recurrence steps
#pragma unroll
    for (int tt = 0; tt < 16; ++tt) {
      float dl = sdel[cur][tt][ci];
      float uu = su[cur][tt][ci];
      float dA = __expf(dl * Adn);
      float dBu = dl * sB[cur][tt][n] * uu;
      h = __builtin_fmaf(dA, h, dBu);
      sp[tt][ci][n] = h * sC[cur][tt][n];
    }
    __syncthreads();
    // phase B: reduce over states + epilogue; thread -> (t=lt, channel=lc)
    {
      const facc4* p4 = (const facc4*)(&sp[lt][lc][0]);
      facc4 s0 = p4[0], s1 = p4[1], s2 = p4[2], s3 = p4[3];
      facc4 ss = s0 + s1 + s2 + s3;
      float ysum = ss.x + ss.y + ss.z + ss.w;
      float uu = su[cur][lt][lc];
      float rs = sres[cur][lt][lc];
      float yv = (ysum + uu * Dd) * (rs * sigmoidf_(rs));
      const size_t row = rb + (size_t)c * 16 + lt;
      ybf[row * DI + d0 + lc] = f2bf(yv);
    }
    if (nxt) {
      const int nb = cur ^ 1;
      sdel[nb][lt][lc] = r0; su[nb][lt][lc] = r1; sres[nb][lt][lc] = r2;
      sB[nb][lt][lc] = r3; sC[nb][lt][lc] = r4;
    }
    __syncthreads();
  }
}

// ---------------- launcher ----------------
extern "C" void kernel_launch(void* const* d_in, const int* in_sizes, int n_in,
                              void* d_out, int out_size, void* d_ws, size_t ws_size,
                              hipStream_t stream) {
  const float* x     = (const float*)d_in[0];
  const float* W_in  = (const float*)d_in[1];
  const float* convw = (const float*)d_in[2];
  const float* convb = (const float*)d_in[3];
  const float* W_x   = (const float*)d_in[4];
  const float* W_dt  = (const float*)d_in[5];
  const float* b_dt  = (const float*)d_in[6];
  const float* A_log = (const float*)d_in[7];
  const float* Dv    = (const float*)d_in[8];
  const float* W_out = (const float*)d_in[9];
  float* out = (float*)d_out;

  char* ws = (char*)d_ws;
  size_t off = 0;
  auto alloc = [&](size_t bytes) { char* p = ws + off; off += (bytes + 255) & ~(size_t)255; return p; };
  unsigned short* xbf   = (unsigned short*)alloc((size_t)MM * DM * 2);
  unsigned short* Wint  = (unsigned short*)alloc((size_t)(2 * DI) * DM * 2);
  float*          xr    = (float*)alloc((size_t)MM * (2 * DI) * 4);
  float*          uf    = (float*)alloc((size_t)MM * DI * 4);
  unsigned short* ubf   = (unsigned short*)alloc((size_t)MM * DI * 2);
  unsigned short* Wxt   = (unsigned short*)alloc((size_t)96 * DI * 2);
  float*          dbc   = (float*)alloc((size_t)MM * 96 * 4);
  unsigned short* drbf  = (unsigned short*)alloc((size_t)MM * DTR * 2);
  unsigned short* Wdtt  = (unsigned short*)alloc((size_t)DI * DTR * 2);
  float*          delta = (float*)alloc((size_t)MM * DI * 4);
  unsigned short* ybf   = (unsigned short*)alloc((size_t)MM * DI * 2);
  unsigned short* Woutt = (unsigned short*)alloc((size_t)DM * DI * 2);

  // converts / transposes (every call — no static state)
  cvt_bf16<<<(MM * DM / 4) / 256, 256, 0, stream>>>(x, xbf, MM * DM);
  transpose_cvt<<<dim3((2 * DI) / 32, DM / 32), dim3(32, 8), 0, stream>>>(W_in, Wint, DM, 2 * DI);
  transpose_cvt<<<dim3(96 / 32, DI / 32), dim3(32, 8), 0, stream>>>(W_x, Wxt, DI, 96);
  transpose_cvt<<<dim3(DI / 32, DTR / 32), dim3(32, 8), 0, stream>>>(W_dt, Wdtt, DTR, DI);
  transpose_cvt<<<dim3(DM / 32, DI / 32), dim3(32, 8), 0, stream>>>(W_out, Woutt, DI, DM);

  // xr = x @ W_in   (M=4096, N=4096, K=1024)
  gemm_bf16<128, 128, 2, 2, 4, 4, 0><<<dim3((2 * DI) / 128, MM / 128, 1), 256, 0, stream>>>(
      xbf, Wint, xr, nullptr, MM, 2 * DI, DM, DM);

  // u = silu(conv(xi))
  conv_silu<<<dim3(DI / 256, LL / 64, BB), 256, 0, stream>>>(xr, convw, convb, uf, ubf);

  // dbc = u @ W_x   (M=4096, N=96, K=2048) split-K=8, atomic accumulate
  hipMemsetAsync(dbc, 0, (size_t)MM * 96 * 4, stream);
  gemm_bf16<128, 96, 4, 1, 2, 6, 2><<<dim3(1, MM / 128, 8), 256, 0, stream>>>(
      ubf, Wxt, dbc, nullptr, MM, 96, DI, DI / 8);

  // delta_r -> bf16
  extract_dr<<<(MM * DTR) / 256, 256, 0, stream>>>(dbc, drbf);

  // delta = softplus(delta_r @ W_dt + b_dt)   (M=4096, N=2048, K=64)
  gemm_bf16<128, 128, 2, 2, 4, 4, 1><<<dim3(DI / 128, MM / 128, 1), 256, 0, stream>>>(
      drbf, Wdtt, delta, b_dt, MM, DI, DTR, DTR);

  // fused selective scan -> y bf16   (16 channels/block, (BB*DI)/16 = 256 blocks)
  scan_kernel<<<(BB * DI) / 16, 256, 0, stream>>>(delta, dbc, uf, xr, A_log, Dv, ybf);

  // out = y @ W_out   (M=4096, N=1024, K=2048)
  gemm_bf16<128, 128, 2, 2, 4, 4, 0><<<dim3(DM / 128, MM / 128, 1), 256, 0, stream>>>(
      ybf, Woutt, out, nullptr, MM, DM, DI, DI);
}